// Round 1
// baseline (1248.806 us; speedup 1.0000x reference)
//
#include <hip/hip_runtime.h>
#include <cstdint>

#define D_MODEL   768
#define D_STATE   64
#define D_INNER   1536
#define NHEADS    24
#define HEADDIM   64
#define D_PROJ    3248
#define BATCH     2
#define SEQ       1024
#define ROWS      (BATCH*SEQ)   // 2048
#define LN_EPS    1e-5f
#define A_FLOOR   1e-4f

// ---------------------------------------------------------------------------
// GEMM (NT): C[m][n] = sum_k A[m][k] * B[n][k];  A (M,K) row-major, B (N,K)
// row-major. 128x128 tile, BK=16, 256 threads, 8x8 microtile.
// ---------------------------------------------------------------------------
#define BM 128
#define BN 128
#define BK 16
#define LDA_S (BM + 4)
#define LDB_S (BN + 4)

__global__ __launch_bounds__(256) void gemm_nt_f32(const float* __restrict__ A,
                                                   const float* __restrict__ B,
                                                   float* __restrict__ C,
                                                   int M, int N, int K) {
  __shared__ float As[BK * LDA_S];
  __shared__ float Bs[BK * LDB_S];
  const int tid = threadIdx.x;
  const int bm = blockIdx.y * BM;
  const int bn = blockIdx.x * BN;
  const int tm = (tid & 15) * 8;   // 16 m-slots * 8 = 128
  const int tn = (tid >> 4) * 8;   // 16 n-slots * 8 = 128

  float acc[8][8];
#pragma unroll
  for (int i = 0; i < 8; ++i)
#pragma unroll
    for (int j = 0; j < 8; ++j) acc[i][j] = 0.f;

  for (int k0 = 0; k0 < K; k0 += BK) {
    // stage A tile (BM x BK) and B tile (BN x BK), transposed into [k][m]/[k][n]
#pragma unroll
    for (int i = 0; i < 2; ++i) {
      int idx = tid + i * 256;       // 0..511 -> 512 float4 per operand tile
      int row = idx >> 2;            // 0..127
      int kq  = idx & 3;             // 0..3 (float4 within BK=16)
      int gr = bm + row;
      float4 va = make_float4(0.f, 0.f, 0.f, 0.f);
      if (gr < M) va = *(const float4*)(A + (size_t)gr * K + k0 + kq * 4);
      As[(kq * 4 + 0) * LDA_S + row] = va.x;
      As[(kq * 4 + 1) * LDA_S + row] = va.y;
      As[(kq * 4 + 2) * LDA_S + row] = va.z;
      As[(kq * 4 + 3) * LDA_S + row] = va.w;
      int gn = bn + row;
      float4 vb = make_float4(0.f, 0.f, 0.f, 0.f);
      if (gn < N) vb = *(const float4*)(B + (size_t)gn * K + k0 + kq * 4);
      Bs[(kq * 4 + 0) * LDB_S + row] = vb.x;
      Bs[(kq * 4 + 1) * LDB_S + row] = vb.y;
      Bs[(kq * 4 + 2) * LDB_S + row] = vb.z;
      Bs[(kq * 4 + 3) * LDB_S + row] = vb.w;
    }
    __syncthreads();
#pragma unroll
    for (int k = 0; k < BK; ++k) {
      float a[8], bv[8];
      *(float4*)&a[0]  = *(const float4*)&As[k * LDA_S + tm];
      *(float4*)&a[4]  = *(const float4*)&As[k * LDA_S + tm + 4];
      *(float4*)&bv[0] = *(const float4*)&Bs[k * LDB_S + tn];
      *(float4*)&bv[4] = *(const float4*)&Bs[k * LDB_S + tn + 4];
#pragma unroll
      for (int i = 0; i < 8; ++i)
#pragma unroll
        for (int j = 0; j < 8; ++j)
          acc[i][j] = fmaf(a[i], bv[j], acc[i][j]);
    }
    __syncthreads();
  }

#pragma unroll
  for (int i = 0; i < 8; ++i) {
    int row = bm + tm + i;
    if (row < M) {
#pragma unroll
      for (int jq = 0; jq < 2; ++jq) {
        int col = bn + tn + jq * 4;
        if (col < N) {
          *(float4*)(C + (size_t)row * N + col) =
              make_float4(acc[i][jq * 4 + 0], acc[i][jq * 4 + 1],
                          acc[i][jq * 4 + 2], acc[i][jq * 4 + 3]);
        }
      }
    }
  }
}

// ---------------------------------------------------------------------------
// Prep: per token r = b*L+t: LayerNorm(Bp), LayerNorm(Cp) -> BC[r][0..127];
// per head: DT = softplus(dd_dt + dt_bias), A = min(-softplus(dd_A), -1e-4),
// dec = exp(A*DT) -> decDT[(b*nH+h)*L + t] = (dec, DT).
// 64 threads (1 wave) per token.
// ---------------------------------------------------------------------------
__device__ __forceinline__ float softplusf(float x) {
  return (x > 20.f) ? x : log1pf(expf(x));
}

__device__ __forceinline__ float wave_sum64(float v) {
#pragma unroll
  for (int o = 32; o > 0; o >>= 1) v += __shfl_xor(v, o);
  return v;
}

__global__ __launch_bounds__(64) void prep_kernel(
    const float* __restrict__ proj, const float* __restrict__ dt_bias,
    const float* __restrict__ Bg, const float* __restrict__ Bb,
    const float* __restrict__ Cg, const float* __restrict__ Cb,
    float* __restrict__ BC, float2* __restrict__ decDT) {
  const int r = blockIdx.x;           // 0..2047
  const int lane = threadIdx.x;       // 0..63
  const float* p = proj + (size_t)r * D_PROJ;

  float bp = p[2 * D_INNER + lane];
  float cp = p[2 * D_INNER + D_STATE + lane];

  float mb = wave_sum64(bp) * (1.f / 64.f);
  float mc = wave_sum64(cp) * (1.f / 64.f);
  float db = bp - mb, dc = cp - mc;
  float vb = wave_sum64(db * db) * (1.f / 64.f);
  float vc = wave_sum64(dc * dc) * (1.f / 64.f);
  float bn = db * rsqrtf(vb + LN_EPS) * Bg[lane] + Bb[lane];
  float cn = dc * rsqrtf(vc + LN_EPS) * Cg[lane] + Cb[lane];
  BC[(size_t)r * 128 + lane]      = bn;
  BC[(size_t)r * 128 + 64 + lane] = cn;

  if (lane < NHEADS) {
    float ddt = p[2 * D_INNER + 2 * D_STATE + lane];
    float dA  = p[2 * D_INNER + 2 * D_STATE + NHEADS + lane];
    float DT = softplusf(ddt + dt_bias[lane]);
    float Aa = fminf(-softplusf(dA), -A_FLOOR);
    float dec = expf(Aa * DT);
    int b = r >> 10;      // / SEQ
    int t = r & 1023;     // % SEQ
    decDT[((size_t)(b * NHEADS + lane) << 10) + t] = make_float2(dec, DT);
  }
}

// ---------------------------------------------------------------------------
// Scan: one wave per (b,h). Lane p owns state row h[p][0..63] in registers.
// Per step: h[n] = dec*h[n] + (DT*x_p)*Bn[n]; y_p = sum_n h[n]*Cn[n] + D_h*x_p
// Then fuse the silu gate: Ybuf = y * silu(z).
// ---------------------------------------------------------------------------
__global__ __launch_bounds__(64) void scan_kernel(
    const float* __restrict__ proj, const float* __restrict__ BC,
    const float2* __restrict__ decDT, const float* __restrict__ Dv,
    float* __restrict__ Ybuf) {
  const int bh = blockIdx.x;          // 0..47
  const int b = bh / NHEADS;
  const int hh = bh % NHEADS;
  const int lane = threadIdx.x;       // p

  float h[64];
#pragma unroll
  for (int i = 0; i < 64; ++i) h[i] = 0.f;

  const float Dh = Dv[hh];
  const float* px = proj + (size_t)b * SEQ * D_PROJ + D_INNER + hh * HEADDIM + lane;
  const float* pz = proj + (size_t)b * SEQ * D_PROJ + hh * HEADDIM + lane;
  const float4* bc = (const float4*)(BC + (size_t)b * SEQ * 128);
  const float2* dd = decDT + ((size_t)bh << 10);
  float* y = Ybuf + (size_t)b * SEQ * D_INNER + hh * HEADDIM + lane;

  for (int t = 0; t < SEQ; ++t) {
    float xv = px[(size_t)t * D_PROJ];
    float zv = pz[(size_t)t * D_PROJ];
    float2 d2 = dd[t];                  // lane-uniform -> s_load
    float dec = d2.x;
    float bx = d2.y * xv;
    float accv = 0.f;
    const float4* bct = bc + (size_t)t * 32;  // 32 float4 = Bn[64],Cn[64]
#pragma unroll
    for (int n4 = 0; n4 < 16; ++n4) {
      float4 bnv = bct[n4];
      float4 cnv = bct[16 + n4];
      h[4 * n4 + 0] = fmaf(dec, h[4 * n4 + 0], bx * bnv.x);
      accv = fmaf(h[4 * n4 + 0], cnv.x, accv);
      h[4 * n4 + 1] = fmaf(dec, h[4 * n4 + 1], bx * bnv.y);
      accv = fmaf(h[4 * n4 + 1], cnv.y, accv);
      h[4 * n4 + 2] = fmaf(dec, h[4 * n4 + 2], bx * bnv.z);
      accv = fmaf(h[4 * n4 + 2], cnv.z, accv);
      h[4 * n4 + 3] = fmaf(dec, h[4 * n4 + 3], bx * bnv.w);
      accv = fmaf(h[4 * n4 + 3], cnv.w, accv);
    }
    float yv = accv + Dh * xv;
    float sz = zv / (1.f + expf(-zv));  // silu(z)
    y[(size_t)t * D_INNER] = yv * sz;
  }
}

// ---------------------------------------------------------------------------
// Launch
// ---------------------------------------------------------------------------
extern "C" void kernel_launch(void* const* d_in, const int* in_sizes, int n_in,
                              void* d_out, int out_size, void* d_ws, size_t ws_size,
                              hipStream_t stream) {
  const float* u       = (const float*)d_in[0];   // (2,1024,768)
  const float* Win     = (const float*)d_in[1];   // (3248,768)
  const float* Wout    = (const float*)d_in[2];   // (768,1536)
  const float* dt_bias = (const float*)d_in[3];   // (24,)
  const float* Dv      = (const float*)d_in[4];   // (24,)
  const float* Bg      = (const float*)d_in[5];
  const float* Bb      = (const float*)d_in[6];
  const float* Cg      = (const float*)d_in[7];
  const float* Cb      = (const float*)d_in[8];
  float* out = (float*)d_out;                     // (2,1024,768)

  float* ws = (float*)d_ws;
  float*  proj  = ws;                                   // 2048*3248
  float*  BC    = proj + (size_t)ROWS * D_PROJ;         // 2048*128
  float2* decDT = (float2*)(BC + (size_t)ROWS * 128);   // 48*1024 float2
  float*  Ybuf  = (float*)decDT + (size_t)2 * BATCH * NHEADS * SEQ; // 2048*1536

  // 1) proj = u @ Win.T
  dim3 g1((D_PROJ + BN - 1) / BN, ROWS / BM);  // (26,16)
  gemm_nt_f32<<<g1, 256, 0, stream>>>(u, Win, proj, ROWS, D_PROJ, D_MODEL);

  // 2) LN(B), LN(C), DT/dec
  prep_kernel<<<ROWS, 64, 0, stream>>>(proj, dt_bias, Bg, Bb, Cg, Cb, BC, decDT);

  // 3) selective scan + silu gate
  scan_kernel<<<BATCH * NHEADS, 64, 0, stream>>>(proj, BC, decDT, Dv, Ybuf);

  // 4) out = Ybuf @ Wout.T
  dim3 g2((D_MODEL + BN - 1) / BN, ROWS / BM);  // (6,16)
  gemm_nt_f32<<<g2, 256, 0, stream>>>(Ybuf, Wout, out, ROWS, D_MODEL, D_INNER);
}

// Round 2
// 441.455 us; speedup vs baseline: 2.8288x; 2.8288x over previous
//
#include <hip/hip_runtime.h>
#include <cstdint>

#define D_MODEL   768
#define D_STATE   64
#define D_INNER   1536
#define NHEADS    24
#define HEADDIM   64
#define D_PROJ    3248
#define BATCH     2
#define SEQ       1024
#define ROWS      (BATCH*SEQ)   // 2048
#define LN_EPS    1e-5f
#define A_FLOOR   1e-4f
#define QC        64            // chunk length
#define NCH       (SEQ/QC)      // 16
#define LDT       68            // padded LDS stride (floats), 16B-aligned rows

// ---------------------------------------------------------------------------
// GEMM (NT): C[m][n] = sum_k A[m][k] * B[n][k]
// ---------------------------------------------------------------------------
#define BM 128
#define BN 128
#define BK 16
#define LDA_S (BM + 4)
#define LDB_S (BN + 4)

__global__ __launch_bounds__(256) void gemm_nt_f32(const float* __restrict__ A,
                                                   const float* __restrict__ B,
                                                   float* __restrict__ C,
                                                   int M, int N, int K) {
  __shared__ float As[BK * LDA_S];
  __shared__ float Bs[BK * LDB_S];
  const int tid = threadIdx.x;
  const int bm = blockIdx.y * BM;
  const int bn = blockIdx.x * BN;
  const int tm = (tid & 15) * 8;
  const int tn = (tid >> 4) * 8;

  float acc[8][8];
#pragma unroll
  for (int i = 0; i < 8; ++i)
#pragma unroll
    for (int j = 0; j < 8; ++j) acc[i][j] = 0.f;

  for (int k0 = 0; k0 < K; k0 += BK) {
#pragma unroll
    for (int i = 0; i < 2; ++i) {
      int idx = tid + i * 256;
      int row = idx >> 2;
      int kq  = idx & 3;
      int gr = bm + row;
      float4 va = make_float4(0.f, 0.f, 0.f, 0.f);
      if (gr < M) va = *(const float4*)(A + (size_t)gr * K + k0 + kq * 4);
      As[(kq * 4 + 0) * LDA_S + row] = va.x;
      As[(kq * 4 + 1) * LDA_S + row] = va.y;
      As[(kq * 4 + 2) * LDA_S + row] = va.z;
      As[(kq * 4 + 3) * LDA_S + row] = va.w;
      int gn = bn + row;
      float4 vb = make_float4(0.f, 0.f, 0.f, 0.f);
      if (gn < N) vb = *(const float4*)(B + (size_t)gn * K + k0 + kq * 4);
      Bs[(kq * 4 + 0) * LDB_S + row] = vb.x;
      Bs[(kq * 4 + 1) * LDB_S + row] = vb.y;
      Bs[(kq * 4 + 2) * LDB_S + row] = vb.z;
      Bs[(kq * 4 + 3) * LDB_S + row] = vb.w;
    }
    __syncthreads();
#pragma unroll
    for (int k = 0; k < BK; ++k) {
      float a[8], bv[8];
      *(float4*)&a[0]  = *(const float4*)&As[k * LDA_S + tm];
      *(float4*)&a[4]  = *(const float4*)&As[k * LDA_S + tm + 4];
      *(float4*)&bv[0] = *(const float4*)&Bs[k * LDB_S + tn];
      *(float4*)&bv[4] = *(const float4*)&Bs[k * LDB_S + tn + 4];
#pragma unroll
      for (int i = 0; i < 8; ++i)
#pragma unroll
        for (int j = 0; j < 8; ++j)
          acc[i][j] = fmaf(a[i], bv[j], acc[i][j]);
    }
    __syncthreads();
  }

#pragma unroll
  for (int i = 0; i < 8; ++i) {
    int row = bm + tm + i;
    if (row < M) {
#pragma unroll
      for (int jq = 0; jq < 2; ++jq) {
        int col = bn + tn + jq * 4;
        if (col < N) {
          *(float4*)(C + (size_t)row * N + col) =
              make_float4(acc[i][jq * 4 + 0], acc[i][jq * 4 + 1],
                          acc[i][jq * 4 + 2], acc[i][jq * 4 + 3]);
        }
      }
    }
  }
}

// ---------------------------------------------------------------------------
// Prep: LN(B), LN(C) -> BC; a = A*DT (log-decay), DT -> aDT
// ---------------------------------------------------------------------------
__device__ __forceinline__ float softplusf(float x) {
  return (x > 20.f) ? x : log1pf(expf(x));
}

__device__ __forceinline__ float wave_sum64(float v) {
#pragma unroll
  for (int o = 32; o > 0; o >>= 1) v += __shfl_xor(v, o);
  return v;
}

__global__ __launch_bounds__(64) void prep_kernel(
    const float* __restrict__ proj, const float* __restrict__ dt_bias,
    const float* __restrict__ Bg, const float* __restrict__ Bb,
    const float* __restrict__ Cg, const float* __restrict__ Cb,
    float* __restrict__ BC, float2* __restrict__ aDT) {
  const int r = blockIdx.x;
  const int lane = threadIdx.x;
  const float* p = proj + (size_t)r * D_PROJ;

  float bp = p[2 * D_INNER + lane];
  float cp = p[2 * D_INNER + D_STATE + lane];

  float mb = wave_sum64(bp) * (1.f / 64.f);
  float mc = wave_sum64(cp) * (1.f / 64.f);
  float db = bp - mb, dc = cp - mc;
  float vb = wave_sum64(db * db) * (1.f / 64.f);
  float vc = wave_sum64(dc * dc) * (1.f / 64.f);
  float bn = db * rsqrtf(vb + LN_EPS) * Bg[lane] + Bb[lane];
  float cn = dc * rsqrtf(vc + LN_EPS) * Cg[lane] + Cb[lane];
  BC[(size_t)r * 128 + lane]      = bn;
  BC[(size_t)r * 128 + 64 + lane] = cn;

  if (lane < NHEADS) {
    float ddt = p[2 * D_INNER + 2 * D_STATE + lane];
    float dA  = p[2 * D_INNER + 2 * D_STATE + NHEADS + lane];
    float DT = softplusf(ddt + dt_bias[lane]);
    float Aa = fminf(-softplusf(dA), -A_FLOOR);
    int b = r >> 10;
    int t = r & 1023;
    aDT[((size_t)(b * NHEADS + lane) << 10) + t] = make_float2(Aa * DT, DT);
  }
}

// ---------------------------------------------------------------------------
// Inclusive prefix-sum of a over the chunk -> csum (lane t), wave64 scan
// ---------------------------------------------------------------------------
__device__ __forceinline__ float wave_prefix_incl(float v, int lane) {
#pragma unroll
  for (int o = 1; o < 64; o <<= 1) {
    float w = __shfl_up(v, o);
    if (lane >= o) v += w;
  }
  return v;
}

// ---------------------------------------------------------------------------
// chunk_state: T_c[n][p] = sum_s DT_s*exp(csum_end - csum_s) * B_s[n]*x_s[p]
// E_c = exp(csum_end). Grid: bh*NCH + c (768 blocks), 256 threads.
// ---------------------------------------------------------------------------
__global__ __launch_bounds__(256) void chunk_state_kernel(
    const float* __restrict__ proj, const float* __restrict__ BC,
    const float2* __restrict__ aDT, float* __restrict__ Tbuf,
    float* __restrict__ Ebuf) {
  const int blk = blockIdx.x;
  const int c = blk & (NCH - 1), bh = blk >> 4;
  const int b = bh / NHEADS, hh = bh % NHEADS;
  const int tid = threadIdx.x;

  __shared__ float Bs[QC][LDT];   // [s][n]
  __shared__ float Xs[QC][LDT];   // [s][p] * coeff_s
  __shared__ float coeff[QC];
  __shared__ float etot[1];

  if (tid < 64) {
    float2 ad = aDT[((size_t)bh << 10) + c * QC + tid];
    float cs = wave_prefix_incl(ad.x, tid);
    float tot = __shfl(cs, 63);
    coeff[tid] = ad.y * __expf(tot - cs);
    if (tid == 63) etot[0] = __expf(tot);
  }
  __syncthreads();

  for (int i = tid; i < 1024; i += 256) {
    int s = i >> 4;
    int q = (i & 15) * 4;
    int r = b * SEQ + c * QC + s;
    *(float4*)&Bs[s][q] = *(const float4*)(BC + (size_t)r * 128 + q);
    float4 xv = *(const float4*)(proj + (size_t)r * D_PROJ + D_INNER + hh * 64 + q);
    float cf = coeff[s];
    xv.x *= cf; xv.y *= cf; xv.z *= cf; xv.w *= cf;
    *(float4*)&Xs[s][q] = xv;
  }
  __syncthreads();

  const int ni = (tid & 15) * 4, pi = (tid >> 4) * 4;
  float acc[4][4];
#pragma unroll
  for (int i = 0; i < 4; ++i)
#pragma unroll
    for (int j = 0; j < 4; ++j) acc[i][j] = 0.f;

  for (int s = 0; s < QC; ++s) {
    float bn[4], xp[4];
    *(float4*)bn = *(float4*)&Bs[s][ni];
    *(float4*)xp = *(float4*)&Xs[s][pi];
#pragma unroll
    for (int i = 0; i < 4; ++i)
#pragma unroll
      for (int j = 0; j < 4; ++j)
        acc[i][j] = fmaf(bn[i], xp[j], acc[i][j]);
  }

  float* T = Tbuf + (size_t)blk * 4096;
#pragma unroll
  for (int i = 0; i < 4; ++i)
    *(float4*)(T + (size_t)(ni + i) * 64 + pi) =
        make_float4(acc[i][0], acc[i][1], acc[i][2], acc[i][3]);
  if (tid == 0) Ebuf[blk] = etot[0];
}

// ---------------------------------------------------------------------------
// interchunk: S_in[c+1] = E_c * S_in[c] + T_c, store S_in per chunk.
// Grid: 48*4 blocks, 256 threads, float4 per thread.
// ---------------------------------------------------------------------------
__global__ __launch_bounds__(256) void interchunk_kernel(
    const float* __restrict__ Tbuf, const float* __restrict__ Ebuf,
    float* __restrict__ Sinbuf) {
  const int bh = blockIdx.x >> 2, part = blockIdx.x & 3;
  const int tid = threadIdx.x;
  const size_t eo = (size_t)part * 1024 + tid * 4;
  float4 s = make_float4(0.f, 0.f, 0.f, 0.f);
#pragma unroll
  for (int c = 0; c < NCH; ++c) {
    size_t off = ((size_t)(bh * NCH + c)) * 4096 + eo;
    *(float4*)(Sinbuf + off) = s;
    float E = Ebuf[bh * NCH + c];
    float4 t4 = *(const float4*)(Tbuf + off);
    s.x = fmaf(E, s.x, t4.x);
    s.y = fmaf(E, s.y, t4.y);
    s.z = fmaf(E, s.z, t4.z);
    s.w = fmaf(E, s.w, t4.w);
  }
}

// ---------------------------------------------------------------------------
// chunk_output: Y[t][p] = sum_{s<=t} exp(csum_t-csum_s)*DT_s*(C_t.B_s)*x_s[p]
//                        + exp(csum_t)*(C_t . S_in)[p] + D_h*x_t[p]
// then Ybuf = Y * silu(z). Grid 768 blocks, 256 threads.
// ---------------------------------------------------------------------------
__global__ __launch_bounds__(256) void chunk_output_kernel(
    const float* __restrict__ proj, const float* __restrict__ BC,
    const float2* __restrict__ aDT, const float* __restrict__ Sinbuf,
    const float* __restrict__ Dv, float* __restrict__ Ybuf) {
  const int blk = blockIdx.x;
  const int c = blk & (NCH - 1), bh = blk >> 4;
  const int b = bh / NHEADS, hh = bh % NHEADS;
  const int tid = threadIdx.x;

  __shared__ float smem[3 * 64 * LDT];
  __shared__ float csum[QC];
  __shared__ float DTs[QC];
  float (*CcT)[LDT] = (float(*)[LDT])smem;               // [n][t]
  float (*BcT)[LDT] = (float(*)[LDT])(smem + 64 * LDT);  // [n][s]
  float (*Sin)[LDT] = (float(*)[LDT])(smem + 2 * 64 * LDT);  // [n][p]
  float (*Wb)[LDT]  = CcT;   // reuse after phase 1: [s][t]
  float (*Xs)[LDT]  = BcT;   // reuse after phase 1: [s][p]

  if (tid < 64) {
    float2 ad = aDT[((size_t)bh << 10) + c * QC + tid];
    csum[tid] = wave_prefix_incl(ad.x, tid);
    DTs[tid] = ad.y;
  }

  // stage CcT, BcT (transposed), Sin (direct)
  const size_t sin_base = (size_t)blk * 4096;
  for (int i = tid; i < 1024; i += 256) {
    int tt = i >> 4;
    int q = (i & 15) * 4;
    int r = b * SEQ + c * QC + tt;
    float4 bv = *(const float4*)(BC + (size_t)r * 128 + q);
    float4 cv = *(const float4*)(BC + (size_t)r * 128 + 64 + q);
    BcT[q + 0][tt] = bv.x; BcT[q + 1][tt] = bv.y;
    BcT[q + 2][tt] = bv.z; BcT[q + 3][tt] = bv.w;
    CcT[q + 0][tt] = cv.x; CcT[q + 1][tt] = cv.y;
    CcT[q + 2][tt] = cv.z; CcT[q + 3][tt] = cv.w;
    *(float4*)&Sin[tt][q] = *(const float4*)(Sinbuf + sin_base + (size_t)tt * 64 + q);
  }
  __syncthreads();

  const int ti = (tid & 15) * 4, si = (tid >> 4) * 4;
  float acc1[4][4], acc2[4][4];
#pragma unroll
  for (int i = 0; i < 4; ++i)
#pragma unroll
    for (int j = 0; j < 4; ++j) { acc1[i][j] = 0.f; acc2[i][j] = 0.f; }

  // phase 1 (fused): G = Cc @ Bc^T,  CS = Cc @ S_in   (inner dim n)
  for (int n = 0; n < 64; ++n) {
    float cv[4], bv[4], sv[4];
    *(float4*)cv = *(float4*)&CcT[n][ti];
    *(float4*)bv = *(float4*)&BcT[n][si];
    *(float4*)sv = *(float4*)&Sin[n][si];
#pragma unroll
    for (int i = 0; i < 4; ++i)
#pragma unroll
      for (int j = 0; j < 4; ++j) {
        acc1[i][j] = fmaf(cv[i], bv[j], acc1[i][j]);
        acc2[i][j] = fmaf(cv[i], sv[j], acc2[i][j]);
      }
  }
  __syncthreads();  // done reading CcT/BcT/Sin

  // phase 1.5: W^T = mask(G) -> Wb[s][t];  acc2 *= exp(csum_t);  stage Xs
#pragma unroll
  for (int j = 0; j < 4; ++j) {
    int s = si + j;
    float dts = DTs[s], cs = csum[s];
    float w4[4];
#pragma unroll
    for (int i = 0; i < 4; ++i) {
      int t = ti + i;
      w4[i] = (s <= t) ? acc1[i][j] * __expf(csum[t] - cs) * dts : 0.f;
    }
    *(float4*)&Wb[s][ti] = *(float4*)w4;
  }
#pragma unroll
  for (int i = 0; i < 4; ++i) {
    float d = __expf(csum[ti + i]);
#pragma unroll
    for (int j = 0; j < 4; ++j) acc2[i][j] *= d;
  }
  for (int i = tid; i < 1024; i += 256) {
    int s = i >> 4;
    int q = (i & 15) * 4;
    int r = b * SEQ + c * QC + s;
    *(float4*)&Xs[s][q] = *(const float4*)(proj + (size_t)r * D_PROJ + D_INNER + hh * 64 + q);
  }
  __syncthreads();

  // phase 2: Y += W^T(s,t)^T @ Xs  (inner dim s)
  for (int s = 0; s < 64; ++s) {
    float wv[4], xv[4];
    *(float4*)wv = *(float4*)&Wb[s][ti];
    *(float4*)xv = *(float4*)&Xs[s][si];
#pragma unroll
    for (int i = 0; i < 4; ++i)
#pragma unroll
      for (int j = 0; j < 4; ++j)
        acc2[i][j] = fmaf(wv[i], xv[j], acc2[i][j]);
  }

  // epilogue: + D*x, silu(z) gate, write
  const float Dh = Dv[hh];
#pragma unroll
  for (int i = 0; i < 4; ++i) {
    int t = ti + i;
    int r = b * SEQ + c * QC + t;
    float zv[4];
    *(float4*)zv = *(const float4*)(proj + (size_t)r * D_PROJ + hh * 64 + si);
    float o4[4];
#pragma unroll
    for (int j = 0; j < 4; ++j) {
      float x = Xs[t][si + j];
      float y = acc2[i][j] + Dh * x;
      float z = zv[j];
      o4[j] = y * (z / (1.f + __expf(-z)));
    }
    *(float4*)(Ybuf + (size_t)r * D_INNER + hh * 64 + si) = *(float4*)o4;
  }
}

// ---------------------------------------------------------------------------
// Launch
// ---------------------------------------------------------------------------
extern "C" void kernel_launch(void* const* d_in, const int* in_sizes, int n_in,
                              void* d_out, int out_size, void* d_ws, size_t ws_size,
                              hipStream_t stream) {
  const float* u       = (const float*)d_in[0];
  const float* Win     = (const float*)d_in[1];
  const float* Wout    = (const float*)d_in[2];
  const float* dt_bias = (const float*)d_in[3];
  const float* Dv      = (const float*)d_in[4];
  const float* Bg      = (const float*)d_in[5];
  const float* Bb      = (const float*)d_in[6];
  const float* Cg      = (const float*)d_in[7];
  const float* Cb      = (const float*)d_in[8];
  float* out = (float*)d_out;

  float* ws = (float*)d_ws;
  float*  proj   = ws;                                    // 2048*3248
  float*  BC     = proj + (size_t)ROWS * D_PROJ;          // 2048*128
  float2* aDT    = (float2*)(BC + (size_t)ROWS * 128);    // 48*1024 float2
  float*  Tbuf   = (float*)aDT + (size_t)2 * BATCH * NHEADS * SEQ;  // 768*4096
  float*  Ybuf   = Tbuf;  // alias: Tbuf dead after interchunk, Ybuf written after
  float*  Ebuf   = Tbuf + (size_t)BATCH * NHEADS * NCH * 4096;      // 768 (pad 1024)
  float*  Sinbuf = Ebuf + 1024;                           // 768*4096

  // 1) proj = u @ Win.T
  dim3 g1((D_PROJ + BN - 1) / BN, ROWS / BM);
  gemm_nt_f32<<<g1, 256, 0, stream>>>(u, Win, proj, ROWS, D_PROJ, D_MODEL);

  // 2) LN(B), LN(C), a/DT
  prep_kernel<<<ROWS, 64, 0, stream>>>(proj, dt_bias, Bg, Bb, Cg, Cb, BC, aDT);

  // 3) chunked scan
  chunk_state_kernel<<<BATCH * NHEADS * NCH, 256, 0, stream>>>(proj, BC, aDT, Tbuf, Ebuf);
  interchunk_kernel<<<BATCH * NHEADS * 4, 256, 0, stream>>>(Tbuf, Ebuf, Sinbuf);
  chunk_output_kernel<<<BATCH * NHEADS * NCH, 256, 0, stream>>>(proj, BC, aDT, Sinbuf, Dv, Ybuf);

  // 4) out = Ybuf @ Wout.T
  dim3 g2((D_MODEL + BN - 1) / BN, ROWS / BM);
  gemm_nt_f32<<<g2, 256, 0, stream>>>(Ybuf, Wout, out, ROWS, D_MODEL, D_INNER);
}

// Round 3
// 135.150 us; speedup vs baseline: 9.2402x; 3.2664x over previous
//
#include <hip/hip_runtime.h>
#include <cstdint>

#define D_MODEL   768
#define D_STATE   64
#define D_INNER   1536
#define NHEADS    24
#define HEADDIM   64
#define D_PROJ    3248
#define BATCH     2
#define SEQ       1024
#define ROWS      (BATCH*SEQ)   // 2048
#define LN_EPS    1e-5f
#define A_FLOOR   1e-4f
#define QC        64            // chunk length
#define NCH       (SEQ/QC)      // 16
#define LDT       68            // padded LDS stride (floats)
#define NPAD_WIN  3328          // 3248 padded to multiple of 128

typedef __attribute__((ext_vector_type(8))) short short8;
typedef __attribute__((ext_vector_type(4))) float f32x4;

// round-to-nearest-even f32 -> bf16 bits
__device__ __forceinline__ unsigned short f2bf(float f) {
  union { float f; uint32_t u; } v; v.f = f;
  uint32_t r = (v.u + 0x7FFFu + ((v.u >> 16) & 1u)) >> 16;
  return (unsigned short)r;
}

__device__ __forceinline__ void gload_lds16(const void* g, void* l) {
  __builtin_amdgcn_global_load_lds(
      (const __attribute__((address_space(1))) unsigned int*)g,
      (__attribute__((address_space(3))) unsigned int*)l, 16, 0, 0);
}

// ---------------------------------------------------------------------------
// Cast f32 -> bf16 with optional row padding (rows >= srcRows write 0).
// One block per row, 256 threads, float4 per thread.
// ---------------------------------------------------------------------------
__global__ __launch_bounds__(256) void cast_bf16_kernel(
    const float* __restrict__ src, unsigned short* __restrict__ dst,
    int cols, int srcRows) {
  const int row = blockIdx.x;
  const bool live = row < srcRows;
  for (int c = threadIdx.x * 4; c < cols; c += 256 * 4) {
    float4 v = make_float4(0.f, 0.f, 0.f, 0.f);
    if (live) v = *(const float4*)(src + (size_t)row * cols + c);
    ushort4 o;
    o.x = f2bf(v.x); o.y = f2bf(v.y); o.z = f2bf(v.z); o.w = f2bf(v.w);
    *(ushort4*)(dst + (size_t)row * cols + c) = o;
  }
}

// ---------------------------------------------------------------------------
// MFMA bf16 GEMM (NT): C[m][n] = sum_k A[m][k]*B[n][k], f32 accumulate.
// A (M,K) bf16 row-major, B (N,K) bf16 row-major, C (M,N) f32.
// Tile TBM x TBN, BK=32, 256 threads = 4 waves (2x2), m97-style structure:
// global_load_lds width-16 staging into chunk-major LDS [4][rows][8bf16].
// ---------------------------------------------------------------------------
template <int TBM, int TBN>
__global__ __launch_bounds__(256) void gemm_bt_bf16(
    const unsigned short* __restrict__ A, const unsigned short* __restrict__ B,
    float* __restrict__ C, int M, int N, int K) {
  constexpr int MF = TBM / 32;     // 16x16 m-frags per wave
  constexpr int NF = TBN / 32;
  constexpr int NSA = TBM / 16;    // 1KB staging segments for A tile
  constexpr int NSB = TBN / 16;
  __shared__ unsigned short Asm[4 * TBM * 8];   // [chunk][row][8]
  __shared__ unsigned short Bsm[4 * TBN * 8];

  const int tid = threadIdx.x;
  const int wv = tid >> 6, lane = tid & 63;
  const int bm = blockIdx.y * TBM, bn = blockIdx.x * TBN;
  const int wm = (wv & 1) * (TBM / 2);
  const int wn = (wv >> 1) * (TBN / 2);
  const int g = lane >> 4, r = lane & 15;

  f32x4 acc[MF][NF];
#pragma unroll
  for (int i = 0; i < MF; ++i)
#pragma unroll
    for (int j = 0; j < NF; ++j) acc[i][j] = (f32x4){0.f, 0.f, 0.f, 0.f};

  for (int k0 = 0; k0 < K; k0 += 32) {
    // stage: each wave handles segments s = wv, wv+4, ...
    for (int s = wv; s < NSA + NSB; s += 4) {
      if (s < NSA) {
        int chunk = s / (TBM / 64);
        int row0 = (s % (TBM / 64)) * 64;
        const unsigned short* src = A + (size_t)(bm + row0 + lane) * K + k0 + chunk * 8;
        gload_lds16(src, (void*)(Asm + s * 512));
      } else {
        int s2 = s - NSA;
        int chunk = s2 / (TBN / 64);
        int row0 = (s2 % (TBN / 64)) * 64;
        const unsigned short* src = B + (size_t)(bn + row0 + lane) * K + k0 + chunk * 8;
        gload_lds16(src, (void*)(Bsm + s2 * 512));
      }
    }
    __syncthreads();   // drains vmcnt (global_load_lds) + lgkm

    short8 a[MF], b[NF];
#pragma unroll
    for (int mf = 0; mf < MF; ++mf)
      a[mf] = *(const short8*)&Asm[g * TBM * 8 + (wm + mf * 16 + r) * 8];
#pragma unroll
    for (int nf = 0; nf < NF; ++nf)
      b[nf] = *(const short8*)&Bsm[g * TBN * 8 + (wn + nf * 16 + r) * 8];
#pragma unroll
    for (int mf = 0; mf < MF; ++mf)
#pragma unroll
      for (int nf = 0; nf < NF; ++nf)
        acc[mf][nf] = __builtin_amdgcn_mfma_f32_16x16x32_bf16(a[mf], b[nf], acc[mf][nf], 0, 0, 0);
    __syncthreads();
  }

  // C write: D row = (lane>>4)*4 + q, col = lane&15 (m89-verified layout)
#pragma unroll
  for (int mf = 0; mf < MF; ++mf) {
#pragma unroll
    for (int nf = 0; nf < NF; ++nf) {
      int col = bn + wn + nf * 16 + r;
      if (col < N) {
#pragma unroll
        for (int q = 0; q < 4; ++q) {
          int row = bm + wm + mf * 16 + g * 4 + q;
          C[(size_t)row * N + col] = acc[mf][nf][q];
        }
      }
    }
  }
}

// ---------------------------------------------------------------------------
// Prep: LN(B), LN(C) -> BC; a = A*DT (log-decay), DT -> aDT
// ---------------------------------------------------------------------------
__device__ __forceinline__ float softplusf(float x) {
  return (x > 20.f) ? x : log1pf(expf(x));
}

__device__ __forceinline__ float wave_sum64(float v) {
#pragma unroll
  for (int o = 32; o > 0; o >>= 1) v += __shfl_xor(v, o);
  return v;
}

__global__ __launch_bounds__(64) void prep_kernel(
    const float* __restrict__ proj, const float* __restrict__ dt_bias,
    const float* __restrict__ Bg, const float* __restrict__ Bb,
    const float* __restrict__ Cg, const float* __restrict__ Cb,
    float* __restrict__ BC, float2* __restrict__ aDT) {
  const int r = blockIdx.x;
  const int lane = threadIdx.x;
  const float* p = proj + (size_t)r * D_PROJ;

  float bp = p[2 * D_INNER + lane];
  float cp = p[2 * D_INNER + D_STATE + lane];

  float mb = wave_sum64(bp) * (1.f / 64.f);
  float mc = wave_sum64(cp) * (1.f / 64.f);
  float db = bp - mb, dc = cp - mc;
  float vb = wave_sum64(db * db) * (1.f / 64.f);
  float vc = wave_sum64(dc * dc) * (1.f / 64.f);
  float bn = db * rsqrtf(vb + LN_EPS) * Bg[lane] + Bb[lane];
  float cn = dc * rsqrtf(vc + LN_EPS) * Cg[lane] + Cb[lane];
  BC[(size_t)r * 128 + lane]      = bn;
  BC[(size_t)r * 128 + 64 + lane] = cn;

  if (lane < NHEADS) {
    float ddt = p[2 * D_INNER + 2 * D_STATE + lane];
    float dA  = p[2 * D_INNER + 2 * D_STATE + NHEADS + lane];
    float DT = softplusf(ddt + dt_bias[lane]);
    float Aa = fminf(-softplusf(dA), -A_FLOOR);
    int b = r >> 10;
    int t = r & 1023;
    aDT[((size_t)(b * NHEADS + lane) << 10) + t] = make_float2(Aa * DT, DT);
  }
}

__device__ __forceinline__ float wave_prefix_incl(float v, int lane) {
#pragma unroll
  for (int o = 1; o < 64; o <<= 1) {
    float w = __shfl_up(v, o);
    if (lane >= o) v += w;
  }
  return v;
}

// ---------------------------------------------------------------------------
// chunk_state: T_c[n][p] = sum_s DT_s*exp(csum_end - csum_s) * B_s[n]*x_s[p]
// ---------------------------------------------------------------------------
__global__ __launch_bounds__(256) void chunk_state_kernel(
    const float* __restrict__ proj, const float* __restrict__ BC,
    const float2* __restrict__ aDT, float* __restrict__ Tbuf,
    float* __restrict__ Ebuf) {
  const int blk = blockIdx.x;
  const int c = blk & (NCH - 1), bh = blk >> 4;
  const int b = bh / NHEADS, hh = bh % NHEADS;
  const int tid = threadIdx.x;

  __shared__ float Bs[QC][LDT];
  __shared__ float Xs[QC][LDT];
  __shared__ float coeff[QC];
  __shared__ float etot[1];

  if (tid < 64) {
    float2 ad = aDT[((size_t)bh << 10) + c * QC + tid];
    float cs = wave_prefix_incl(ad.x, tid);
    float tot = __shfl(cs, 63);
    coeff[tid] = ad.y * __expf(tot - cs);
    if (tid == 63) etot[0] = __expf(tot);
  }
  __syncthreads();

  for (int i = tid; i < 1024; i += 256) {
    int s = i >> 4;
    int q = (i & 15) * 4;
    int r = b * SEQ + c * QC + s;
    *(float4*)&Bs[s][q] = *(const float4*)(BC + (size_t)r * 128 + q);
    float4 xv = *(const float4*)(proj + (size_t)r * D_PROJ + D_INNER + hh * 64 + q);
    float cf = coeff[s];
    xv.x *= cf; xv.y *= cf; xv.z *= cf; xv.w *= cf;
    *(float4*)&Xs[s][q] = xv;
  }
  __syncthreads();

  const int ni = (tid & 15) * 4, pi = (tid >> 4) * 4;
  float acc[4][4];
#pragma unroll
  for (int i = 0; i < 4; ++i)
#pragma unroll
    for (int j = 0; j < 4; ++j) acc[i][j] = 0.f;

  for (int s = 0; s < QC; ++s) {
    float bn[4], xp[4];
    *(float4*)bn = *(float4*)&Bs[s][ni];
    *(float4*)xp = *(float4*)&Xs[s][pi];
#pragma unroll
    for (int i = 0; i < 4; ++i)
#pragma unroll
      for (int j = 0; j < 4; ++j)
        acc[i][j] = fmaf(bn[i], xp[j], acc[i][j]);
  }

  float* T = Tbuf + (size_t)blk * 4096;
#pragma unroll
  for (int i = 0; i < 4; ++i)
    *(float4*)(T + (size_t)(ni + i) * 64 + pi) =
        make_float4(acc[i][0], acc[i][1], acc[i][2], acc[i][3]);
  if (tid == 0) Ebuf[blk] = etot[0];
}

// ---------------------------------------------------------------------------
// interchunk: S_in[c+1] = E_c * S_in[c] + T_c
// ---------------------------------------------------------------------------
__global__ __launch_bounds__(256) void interchunk_kernel(
    const float* __restrict__ Tbuf, const float* __restrict__ Ebuf,
    float* __restrict__ Sinbuf) {
  const int bh = blockIdx.x >> 2, part = blockIdx.x & 3;
  const int tid = threadIdx.x;
  const size_t eo = (size_t)part * 1024 + tid * 4;
  float4 s = make_float4(0.f, 0.f, 0.f, 0.f);
#pragma unroll
  for (int c = 0; c < NCH; ++c) {
    size_t off = ((size_t)(bh * NCH + c)) * 4096 + eo;
    *(float4*)(Sinbuf + off) = s;
    float E = Ebuf[bh * NCH + c];
    float4 t4 = *(const float4*)(Tbuf + off);
    s.x = fmaf(E, s.x, t4.x);
    s.y = fmaf(E, s.y, t4.y);
    s.z = fmaf(E, s.z, t4.z);
    s.w = fmaf(E, s.w, t4.w);
  }
}

// ---------------------------------------------------------------------------
// chunk_output: intra+inter chunk Y, + D*x, silu(z) gate -> bf16 Ybuf
// ---------------------------------------------------------------------------
__global__ __launch_bounds__(256) void chunk_output_kernel(
    const float* __restrict__ proj, const float* __restrict__ BC,
    const float2* __restrict__ aDT, const float* __restrict__ Sinbuf,
    const float* __restrict__ Dv, unsigned short* __restrict__ Ybf) {
  const int blk = blockIdx.x;
  const int c = blk & (NCH - 1), bh = blk >> 4;
  const int b = bh / NHEADS, hh = bh % NHEADS;
  const int tid = threadIdx.x;

  __shared__ float smem[3 * 64 * LDT];
  __shared__ float csum[QC];
  __shared__ float DTs[QC];
  float (*CcT)[LDT] = (float(*)[LDT])smem;
  float (*BcT)[LDT] = (float(*)[LDT])(smem + 64 * LDT);
  float (*Sin)[LDT] = (float(*)[LDT])(smem + 2 * 64 * LDT);
  float (*Wb)[LDT]  = CcT;
  float (*Xs)[LDT]  = BcT;

  if (tid < 64) {
    float2 ad = aDT[((size_t)bh << 10) + c * QC + tid];
    csum[tid] = wave_prefix_incl(ad.x, tid);
    DTs[tid] = ad.y;
  }

  const size_t sin_base = (size_t)blk * 4096;
  for (int i = tid; i < 1024; i += 256) {
    int tt = i >> 4;
    int q = (i & 15) * 4;
    int r = b * SEQ + c * QC + tt;
    float4 bv = *(const float4*)(BC + (size_t)r * 128 + q);
    float4 cv = *(const float4*)(BC + (size_t)r * 128 + 64 + q);
    BcT[q + 0][tt] = bv.x; BcT[q + 1][tt] = bv.y;
    BcT[q + 2][tt] = bv.z; BcT[q + 3][tt] = bv.w;
    CcT[q + 0][tt] = cv.x; CcT[q + 1][tt] = cv.y;
    CcT[q + 2][tt] = cv.z; CcT[q + 3][tt] = cv.w;
    *(float4*)&Sin[tt][q] = *(const float4*)(Sinbuf + sin_base + (size_t)tt * 64 + q);
  }
  __syncthreads();

  const int ti = (tid & 15) * 4, si = (tid >> 4) * 4;
  float acc1[4][4], acc2[4][4];
#pragma unroll
  for (int i = 0; i < 4; ++i)
#pragma unroll
    for (int j = 0; j < 4; ++j) { acc1[i][j] = 0.f; acc2[i][j] = 0.f; }

  for (int n = 0; n < 64; ++n) {
    float cv[4], bv[4], sv[4];
    *(float4*)cv = *(float4*)&CcT[n][ti];
    *(float4*)bv = *(float4*)&BcT[n][si];
    *(float4*)sv = *(float4*)&Sin[n][si];
#pragma unroll
    for (int i = 0; i < 4; ++i)
#pragma unroll
      for (int j = 0; j < 4; ++j) {
        acc1[i][j] = fmaf(cv[i], bv[j], acc1[i][j]);
        acc2[i][j] = fmaf(cv[i], sv[j], acc2[i][j]);
      }
  }
  __syncthreads();

#pragma unroll
  for (int j = 0; j < 4; ++j) {
    int s = si + j;
    float dts = DTs[s], cs = csum[s];
    float w4[4];
#pragma unroll
    for (int i = 0; i < 4; ++i) {
      int t = ti + i;
      w4[i] = (s <= t) ? acc1[i][j] * __expf(csum[t] - cs) * dts : 0.f;
    }
    *(float4*)&Wb[s][ti] = *(float4*)w4;
  }
#pragma unroll
  for (int i = 0; i < 4; ++i) {
    float d = __expf(csum[ti + i]);
#pragma unroll
    for (int j = 0; j < 4; ++j) acc2[i][j] *= d;
  }
  for (int i = tid; i < 1024; i += 256) {
    int s = i >> 4;
    int q = (i & 15) * 4;
    int r = b * SEQ + c * QC + s;
    *(float4*)&Xs[s][q] = *(const float4*)(proj + (size_t)r * D_PROJ + D_INNER + hh * 64 + q);
  }
  __syncthreads();

  for (int s = 0; s < 64; ++s) {
    float wv[4], xv[4];
    *(float4*)wv = *(float4*)&Wb[s][ti];
    *(float4*)xv = *(float4*)&Xs[s][si];
#pragma unroll
    for (int i = 0; i < 4; ++i)
#pragma unroll
      for (int j = 0; j < 4; ++j)
        acc2[i][j] = fmaf(wv[i], xv[j], acc2[i][j]);
  }

  const float Dh = Dv[hh];
#pragma unroll
  for (int i = 0; i < 4; ++i) {
    int t = ti + i;
    int r = b * SEQ + c * QC + t;
    float zv[4];
    *(float4*)zv = *(const float4*)(proj + (size_t)r * D_PROJ + hh * 64 + si);
    ushort4 o;
    unsigned short* op = (unsigned short*)&o;
#pragma unroll
    for (int j = 0; j < 4; ++j) {
      float x = Xs[t][si + j];
      float y = acc2[i][j] + Dh * x;
      float z = zv[j];
      op[j] = f2bf(y * (z / (1.f + __expf(-z))));
    }
    *(ushort4*)(Ybf + (size_t)r * D_INNER + hh * 64 + si) = o;
  }
}

// ---------------------------------------------------------------------------
// Launch
// ---------------------------------------------------------------------------
extern "C" void kernel_launch(void* const* d_in, const int* in_sizes, int n_in,
                              void* d_out, int out_size, void* d_ws, size_t ws_size,
                              hipStream_t stream) {
  const float* u       = (const float*)d_in[0];
  const float* Win     = (const float*)d_in[1];
  const float* Wout    = (const float*)d_in[2];
  const float* dt_bias = (const float*)d_in[3];
  const float* Dv      = (const float*)d_in[4];
  const float* Bg      = (const float*)d_in[5];
  const float* Bb      = (const float*)d_in[6];
  const float* Cg      = (const float*)d_in[7];
  const float* Cb      = (const float*)d_in[8];
  float* out = (float*)d_out;

  float* ws = (float*)d_ws;
  float*  proj    = ws;                                   // 2048*3248
  float*  BC      = proj + (size_t)ROWS * D_PROJ;         // 2048*128
  float*  aDTf    = BC + (size_t)ROWS * 128;              // 48*1024*2
  float2* aDT     = (float2*)aDTf;
  float*  Tbuf    = aDTf + (size_t)2 * BATCH * NHEADS * SEQ;        // 768*4096
  float*  Ebuf    = Tbuf + (size_t)BATCH * NHEADS * NCH * 4096;     // 1024
  float*  Sinbuf  = Ebuf + 1024;                          // 768*4096
  float*  Woutbff = Sinbuf + (size_t)BATCH * NHEADS * NCH * 4096;   // 294912 floats

  // bf16 buffers aliased onto dead f32 regions (lifetimes verified):
  unsigned short* ubf    = (unsigned short*)Sinbuf;  // dead before interchunk writes
  unsigned short* Winbf  = (unsigned short*)Tbuf;    // dead before chunk_state writes
  unsigned short* Ybf    = (unsigned short*)Tbuf;    // Tbuf dead after interchunk
  unsigned short* Woutbf = (unsigned short*)Woutbff; // standalone

  // casts
  cast_bf16_kernel<<<ROWS, 256, 0, stream>>>(u, ubf, D_MODEL, ROWS);
  cast_bf16_kernel<<<NPAD_WIN, 256, 0, stream>>>(Win, Winbf, D_MODEL, D_PROJ);
  cast_bf16_kernel<<<D_MODEL, 256, 0, stream>>>(Wout, Woutbf, D_INNER, D_MODEL);

  // 1) proj = u @ Win.T   (MFMA bf16)
  dim3 g1(NPAD_WIN / 128, ROWS / 128);   // (26,16)
  gemm_bt_bf16<128, 128><<<g1, 256, 0, stream>>>(ubf, Winbf, proj, ROWS, D_PROJ, D_MODEL);

  // 2) LN(B), LN(C), a/DT
  prep_kernel<<<ROWS, 64, 0, stream>>>(proj, dt_bias, Bg, Bb, Cg, Cb, BC, aDT);

  // 3) chunked scan
  chunk_state_kernel<<<BATCH * NHEADS * NCH, 256, 0, stream>>>(proj, BC, aDT, Tbuf, Ebuf);
  interchunk_kernel<<<BATCH * NHEADS * 4, 256, 0, stream>>>(Tbuf, Ebuf, Sinbuf);
  chunk_output_kernel<<<BATCH * NHEADS * NCH, 256, 0, stream>>>(proj, BC, aDT, Sinbuf, Dv, Ybf);

  // 4) out = Ybuf @ Wout.T   (MFMA bf16)
  dim3 g2(D_MODEL / 64, ROWS / 128);     // (12,16)
  gemm_bt_bf16<128, 64><<<g2, 256, 0, stream>>>(Ybf, Woutbf, out, ROWS, D_MODEL, D_INNER);
}

// Round 4
// 127.941 us; speedup vs baseline: 9.7608x; 1.0563x over previous
//
#include <hip/hip_runtime.h>
#include <cstdint>

#define D_MODEL   768
#define D_STATE   64
#define D_INNER   1536
#define NHEADS    24
#define HEADDIM   64
#define D_PROJ    3248
#define BATCH     2
#define SEQ       1024
#define ROWS      (BATCH*SEQ)   // 2048
#define LN_EPS    1e-5f
#define A_FLOOR   1e-4f
#define QC        64            // chunk length
#define NCH       (SEQ/QC)      // 16
#define LDT       68            // padded LDS stride (floats)
#define NPAD_WIN  3328          // 3248 padded to multiple of 128

typedef __attribute__((ext_vector_type(8))) short short8;
typedef __attribute__((ext_vector_type(4))) float f32x4;

// round-to-nearest-even f32 -> bf16 bits
__device__ __forceinline__ unsigned short f2bf(float f) {
  union { float f; uint32_t u; } v; v.f = f;
  uint32_t r = (v.u + 0x7FFFu + ((v.u >> 16) & 1u)) >> 16;
  return (unsigned short)r;
}

__device__ __forceinline__ void gload_lds16(const void* g, void* l) {
  __builtin_amdgcn_global_load_lds(
      (const __attribute__((address_space(1))) unsigned int*)g,
      (__attribute__((address_space(3))) unsigned int*)l, 16, 0, 0);
}

// ---------------------------------------------------------------------------
// Fused casts: u (2048x768), Win (3248->3328 x768 zero-padded), Wout (768x1536)
// One block per destination row.
// ---------------------------------------------------------------------------
__global__ __launch_bounds__(256) void cast_all_kernel(
    const float* __restrict__ u, const float* __restrict__ Win,
    const float* __restrict__ Wout, unsigned short* __restrict__ ubf,
    unsigned short* __restrict__ Winbf, unsigned short* __restrict__ Woutbf) {
  int b = blockIdx.x;
  const float* src; unsigned short* dst; int cols, srcRows, row;
  if (b < ROWS)                 { row = b;                    src = u;    dst = ubf;    cols = D_MODEL; srcRows = ROWS;   }
  else if (b < ROWS + NPAD_WIN) { row = b - ROWS;             src = Win;  dst = Winbf;  cols = D_MODEL; srcRows = D_PROJ; }
  else                          { row = b - ROWS - NPAD_WIN;  src = Wout; dst = Woutbf; cols = D_INNER; srcRows = D_MODEL;}
  const bool live = row < srcRows;
  for (int c = threadIdx.x * 4; c < cols; c += 256 * 4) {
    float4 v = make_float4(0.f, 0.f, 0.f, 0.f);
    if (live) v = *(const float4*)(src + (size_t)row * cols + c);
    ushort4 o;
    o.x = f2bf(v.x); o.y = f2bf(v.y); o.z = f2bf(v.z); o.w = f2bf(v.w);
    *(ushort4*)(dst + (size_t)row * cols + c) = o;
  }
}

// ---------------------------------------------------------------------------
// MFMA bf16 GEMM (NT), double-buffered 2-phase pipeline:
//   prologue: STAGE(buf0,k=0); barrier
//   iter t:   STAGE(buf^1, t+1) ; ds_read+MFMA from buf ; barrier ; flip
// A (M,K) bf16 rm, B (N,K) bf16 rm, C (M,N) f32. 256 thr = 4 waves (2x2).
// LDS layout per operand: [4 k-chunks][rows][8 bf16] so global_load_lds
// segments are linear (1KB per 64-row segment).
// ---------------------------------------------------------------------------
template <int TBM, int TBN>
__global__ __launch_bounds__(256) void gemm_bt_bf16(
    const unsigned short* __restrict__ A, const unsigned short* __restrict__ B,
    float* __restrict__ C, int M, int N, int K) {
  constexpr int MF = TBM / 32;     // 16x16 m-frags per wave
  constexpr int NF = TBN / 32;
  constexpr int NSA = TBM / 16;    // 1KB staging segments
  constexpr int NSB = TBN / 16;
  __shared__ unsigned short Asm[2][TBM * 32];
  __shared__ unsigned short Bsm[2][TBN * 32];

  const int tid = threadIdx.x;
  const int wv = tid >> 6, lane = tid & 63;
  const int bm = blockIdx.y * TBM, bn = blockIdx.x * TBN;
  const int wm = (wv & 1) * (TBM / 2);
  const int wn = (wv >> 1) * (TBN / 2);
  const int g = lane >> 4, r = lane & 15;

  f32x4 acc[MF][NF];
#pragma unroll
  for (int i = 0; i < MF; ++i)
#pragma unroll
    for (int j = 0; j < NF; ++j) acc[i][j] = (f32x4){0.f, 0.f, 0.f, 0.f};

  auto stage = [&](int k0, int buf) {
    for (int s = wv; s < NSA + NSB; s += 4) {
      if (s < NSA) {
        int chunk = s / (TBM / 64);
        int row0 = (s % (TBM / 64)) * 64;
        gload_lds16(A + (size_t)(bm + row0 + lane) * K + k0 + chunk * 8,
                    (void*)(&Asm[buf][s * 512]));
      } else {
        int s2 = s - NSA;
        int chunk = s2 / (TBN / 64);
        int row0 = (s2 % (TBN / 64)) * 64;
        gload_lds16(B + (size_t)(bn + row0 + lane) * K + k0 + chunk * 8,
                    (void*)(&Bsm[buf][s2 * 512]));
      }
    }
  };

  const int kTiles = K >> 5;
  stage(0, 0);
  __syncthreads();
  int cur = 0;
  for (int t = 0; t < kTiles; ++t) {
    if (t + 1 < kTiles) stage((t + 1) << 5, cur ^ 1);  // prefetch next K-tile
    short8 a[MF], b[NF];
#pragma unroll
    for (int mf = 0; mf < MF; ++mf)
      a[mf] = *(const short8*)&Asm[cur][g * TBM * 8 + (wm + mf * 16 + r) * 8];
#pragma unroll
    for (int nf = 0; nf < NF; ++nf)
      b[nf] = *(const short8*)&Bsm[cur][g * TBN * 8 + (wn + nf * 16 + r) * 8];
#pragma unroll
    for (int mf = 0; mf < MF; ++mf)
#pragma unroll
      for (int nf = 0; nf < NF; ++nf)
        acc[mf][nf] = __builtin_amdgcn_mfma_f32_16x16x32_bf16(a[mf], b[nf], acc[mf][nf], 0, 0, 0);
    __syncthreads();   // drains prefetch vmcnt + protects buf reuse
    cur ^= 1;
  }

  // C write: D row = (lane>>4)*4 + q, col = lane&15 (m89-verified layout)
#pragma unroll
  for (int mf = 0; mf < MF; ++mf) {
#pragma unroll
    for (int nf = 0; nf < NF; ++nf) {
      int col = bn + wn + nf * 16 + r;
      if (col < N) {
#pragma unroll
        for (int q = 0; q < 4; ++q) {
          int row = bm + wm + mf * 16 + g * 4 + q;
          C[(size_t)row * N + col] = acc[mf][nf][q];
        }
      }
    }
  }
}

// ---------------------------------------------------------------------------
// Prep: LN(B), LN(C) -> BC; a = A*DT (log-decay), DT -> aDT
// ---------------------------------------------------------------------------
__device__ __forceinline__ float softplusf(float x) {
  return (x > 20.f) ? x : log1pf(expf(x));
}

__device__ __forceinline__ float wave_sum64(float v) {
#pragma unroll
  for (int o = 32; o > 0; o >>= 1) v += __shfl_xor(v, o);
  return v;
}

__global__ __launch_bounds__(64) void prep_kernel(
    const float* __restrict__ proj, const float* __restrict__ dt_bias,
    const float* __restrict__ Bg, const float* __restrict__ Bb,
    const float* __restrict__ Cg, const float* __restrict__ Cb,
    float* __restrict__ BC, float2* __restrict__ aDT) {
  const int r = blockIdx.x;
  const int lane = threadIdx.x;
  const float* p = proj + (size_t)r * D_PROJ;

  float bp = p[2 * D_INNER + lane];
  float cp = p[2 * D_INNER + D_STATE + lane];

  float mb = wave_sum64(bp) * (1.f / 64.f);
  float mc = wave_sum64(cp) * (1.f / 64.f);
  float db = bp - mb, dc = cp - mc;
  float vb = wave_sum64(db * db) * (1.f / 64.f);
  float vc = wave_sum64(dc * dc) * (1.f / 64.f);
  float bn = db * rsqrtf(vb + LN_EPS) * Bg[lane] + Bb[lane];
  float cn = dc * rsqrtf(vc + LN_EPS) * Cg[lane] + Cb[lane];
  BC[(size_t)r * 128 + lane]      = bn;
  BC[(size_t)r * 128 + 64 + lane] = cn;

  if (lane < NHEADS) {
    float ddt = p[2 * D_INNER + 2 * D_STATE + lane];
    float dA  = p[2 * D_INNER + 2 * D_STATE + NHEADS + lane];
    float DT = softplusf(ddt + dt_bias[lane]);
    float Aa = fminf(-softplusf(dA), -A_FLOOR);
    int b = r >> 10;
    int t = r & 1023;
    aDT[((size_t)(b * NHEADS + lane) << 10) + t] = make_float2(Aa * DT, DT);
  }
}

__device__ __forceinline__ float wave_prefix_incl(float v, int lane) {
#pragma unroll
  for (int o = 1; o < 64; o <<= 1) {
    float w = __shfl_up(v, o);
    if (lane >= o) v += w;
  }
  return v;
}

// ---------------------------------------------------------------------------
// chunk_state: T_c[n][p] = sum_s DT_s*exp(csum_end - csum_s) * B_s[n]*x_s[p]
// ---------------------------------------------------------------------------
__global__ __launch_bounds__(256) void chunk_state_kernel(
    const float* __restrict__ proj, const float* __restrict__ BC,
    const float2* __restrict__ aDT, float* __restrict__ Tbuf,
    float* __restrict__ Ebuf) {
  const int blk = blockIdx.x;
  const int c = blk & (NCH - 1), bh = blk >> 4;
  const int b = bh / NHEADS, hh = bh % NHEADS;
  const int tid = threadIdx.x;

  __shared__ float Bs[QC][LDT];
  __shared__ float Xs[QC][LDT];
  __shared__ float coeff[QC];
  __shared__ float etot[1];

  if (tid < 64) {
    float2 ad = aDT[((size_t)bh << 10) + c * QC + tid];
    float cs = wave_prefix_incl(ad.x, tid);
    float tot = __shfl(cs, 63);
    coeff[tid] = ad.y * __expf(tot - cs);
    if (tid == 63) etot[0] = __expf(tot);
  }
  __syncthreads();

  for (int i = tid; i < 1024; i += 256) {
    int s = i >> 4;
    int q = (i & 15) * 4;
    int r = b * SEQ + c * QC + s;
    *(float4*)&Bs[s][q] = *(const float4*)(BC + (size_t)r * 128 + q);
    float4 xv = *(const float4*)(proj + (size_t)r * D_PROJ + D_INNER + hh * 64 + q);
    float cf = coeff[s];
    xv.x *= cf; xv.y *= cf; xv.z *= cf; xv.w *= cf;
    *(float4*)&Xs[s][q] = xv;
  }
  __syncthreads();

  const int ni = (tid & 15) * 4, pi = (tid >> 4) * 4;
  float acc[4][4];
#pragma unroll
  for (int i = 0; i < 4; ++i)
#pragma unroll
    for (int j = 0; j < 4; ++j) acc[i][j] = 0.f;

  for (int s = 0; s < QC; ++s) {
    float bn[4], xp[4];
    *(float4*)bn = *(float4*)&Bs[s][ni];
    *(float4*)xp = *(float4*)&Xs[s][pi];
#pragma unroll
    for (int i = 0; i < 4; ++i)
#pragma unroll
      for (int j = 0; j < 4; ++j)
        acc[i][j] = fmaf(bn[i], xp[j], acc[i][j]);
  }

  float* T = Tbuf + (size_t)blk * 4096;
#pragma unroll
  for (int i = 0; i < 4; ++i)
    *(float4*)(T + (size_t)(ni + i) * 64 + pi) =
        make_float4(acc[i][0], acc[i][1], acc[i][2], acc[i][3]);
  if (tid == 0) Ebuf[blk] = etot[0];
}

// ---------------------------------------------------------------------------
// interchunk: S_in[c+1] = E_c * S_in[c] + T_c
// ---------------------------------------------------------------------------
__global__ __launch_bounds__(256) void interchunk_kernel(
    const float* __restrict__ Tbuf, const float* __restrict__ Ebuf,
    float* __restrict__ Sinbuf) {
  const int bh = blockIdx.x >> 2, part = blockIdx.x & 3;
  const int tid = threadIdx.x;
  const size_t eo = (size_t)part * 1024 + tid * 4;
  float4 s = make_float4(0.f, 0.f, 0.f, 0.f);
#pragma unroll
  for (int c = 0; c < NCH; ++c) {
    size_t off = ((size_t)(bh * NCH + c)) * 4096 + eo;
    *(float4*)(Sinbuf + off) = s;
    float E = Ebuf[bh * NCH + c];
    float4 t4 = *(const float4*)(Tbuf + off);
    s.x = fmaf(E, s.x, t4.x);
    s.y = fmaf(E, s.y, t4.y);
    s.z = fmaf(E, s.z, t4.z);
    s.w = fmaf(E, s.w, t4.w);
  }
}

// ---------------------------------------------------------------------------
// chunk_output: intra+inter chunk Y, + D*x, silu(z) gate -> bf16 Ybuf
// ---------------------------------------------------------------------------
__global__ __launch_bounds__(256) void chunk_output_kernel(
    const float* __restrict__ proj, const float* __restrict__ BC,
    const float2* __restrict__ aDT, const float* __restrict__ Sinbuf,
    const float* __restrict__ Dv, unsigned short* __restrict__ Ybf) {
  const int blk = blockIdx.x;
  const int c = blk & (NCH - 1), bh = blk >> 4;
  const int b = bh / NHEADS, hh = bh % NHEADS;
  const int tid = threadIdx.x;

  __shared__ float smem[3 * 64 * LDT];
  __shared__ float csum[QC];
  __shared__ float DTs[QC];
  float (*CcT)[LDT] = (float(*)[LDT])smem;
  float (*BcT)[LDT] = (float(*)[LDT])(smem + 64 * LDT);
  float (*Sin)[LDT] = (float(*)[LDT])(smem + 2 * 64 * LDT);
  float (*Wb)[LDT]  = CcT;
  float (*Xs)[LDT]  = BcT;

  if (tid < 64) {
    float2 ad = aDT[((size_t)bh << 10) + c * QC + tid];
    csum[tid] = wave_prefix_incl(ad.x, tid);
    DTs[tid] = ad.y;
  }

  const size_t sin_base = (size_t)blk * 4096;
  for (int i = tid; i < 1024; i += 256) {
    int tt = i >> 4;
    int q = (i & 15) * 4;
    int r = b * SEQ + c * QC + tt;
    float4 bv = *(const float4*)(BC + (size_t)r * 128 + q);
    float4 cv = *(const float4*)(BC + (size_t)r * 128 + 64 + q);
    BcT[q + 0][tt] = bv.x; BcT[q + 1][tt] = bv.y;
    BcT[q + 2][tt] = bv.z; BcT[q + 3][tt] = bv.w;
    CcT[q + 0][tt] = cv.x; CcT[q + 1][tt] = cv.y;
    CcT[q + 2][tt] = cv.z; CcT[q + 3][tt] = cv.w;
    *(float4*)&Sin[tt][q] = *(const float4*)(Sinbuf + sin_base + (size_t)tt * 64 + q);
  }
  __syncthreads();

  const int ti = (tid & 15) * 4, si = (tid >> 4) * 4;
  float acc1[4][4], acc2[4][4];
#pragma unroll
  for (int i = 0; i < 4; ++i)
#pragma unroll
    for (int j = 0; j < 4; ++j) { acc1[i][j] = 0.f; acc2[i][j] = 0.f; }

  for (int n = 0; n < 64; ++n) {
    float cv[4], bv[4], sv[4];
    *(float4*)cv = *(float4*)&CcT[n][ti];
    *(float4*)bv = *(float4*)&BcT[n][si];
    *(float4*)sv = *(float4*)&Sin[n][si];
#pragma unroll
    for (int i = 0; i < 4; ++i)
#pragma unroll
      for (int j = 0; j < 4; ++j) {
        acc1[i][j] = fmaf(cv[i], bv[j], acc1[i][j]);
        acc2[i][j] = fmaf(cv[i], sv[j], acc2[i][j]);
      }
  }
  __syncthreads();

#pragma unroll
  for (int j = 0; j < 4; ++j) {
    int s = si + j;
    float dts = DTs[s], cs = csum[s];
    float w4[4];
#pragma unroll
    for (int i = 0; i < 4; ++i) {
      int t = ti + i;
      w4[i] = (s <= t) ? acc1[i][j] * __expf(csum[t] - cs) * dts : 0.f;
    }
    *(float4*)&Wb[s][ti] = *(float4*)w4;
  }
#pragma unroll
  for (int i = 0; i < 4; ++i) {
    float d = __expf(csum[ti + i]);
#pragma unroll
    for (int j = 0; j < 4; ++j) acc2[i][j] *= d;
  }
  for (int i = tid; i < 1024; i += 256) {
    int s = i >> 4;
    int q = (i & 15) * 4;
    int r = b * SEQ + c * QC + s;
    *(float4*)&Xs[s][q] = *(const float4*)(proj + (size_t)r * D_PROJ + D_INNER + hh * 64 + q);
  }
  __syncthreads();

  for (int s = 0; s < 64; ++s) {
    float wv[4], xv[4];
    *(float4*)wv = *(float4*)&Wb[s][ti];
    *(float4*)xv = *(float4*)&Xs[s][si];
#pragma unroll
    for (int i = 0; i < 4; ++i)
#pragma unroll
      for (int j = 0; j < 4; ++j)
        acc2[i][j] = fmaf(wv[i], xv[j], acc2[i][j]);
  }

  const float Dh = Dv[hh];
#pragma unroll
  for (int i = 0; i < 4; ++i) {
    int t = ti + i;
    int r = b * SEQ + c * QC + t;
    float zv[4];
    *(float4*)zv = *(const float4*)(proj + (size_t)r * D_PROJ + hh * 64 + si);
    ushort4 o;
    unsigned short* op = (unsigned short*)&o;
#pragma unroll
    for (int j = 0; j < 4; ++j) {
      float x = Xs[t][si + j];
      float y = acc2[i][j] + Dh * x;
      float z = zv[j];
      op[j] = f2bf(y * (z / (1.f + __expf(-z))));
    }
    *(ushort4*)(Ybf + (size_t)r * D_INNER + hh * 64 + si) = o;
  }
}

// ---------------------------------------------------------------------------
// Launch
// ---------------------------------------------------------------------------
extern "C" void kernel_launch(void* const* d_in, const int* in_sizes, int n_in,
                              void* d_out, int out_size, void* d_ws, size_t ws_size,
                              hipStream_t stream) {
  const float* u       = (const float*)d_in[0];
  const float* Win     = (const float*)d_in[1];
  const float* Wout    = (const float*)d_in[2];
  const float* dt_bias = (const float*)d_in[3];
  const float* Dv      = (const float*)d_in[4];
  const float* Bg      = (const float*)d_in[5];
  const float* Bb      = (const float*)d_in[6];
  const float* Cg      = (const float*)d_in[7];
  const float* Cb      = (const float*)d_in[8];
  float* out = (float*)d_out;

  float* ws = (float*)d_ws;
  float*  proj    = ws;                                   // 2048*3248
  float*  BC      = proj + (size_t)ROWS * D_PROJ;         // 2048*128
  float*  aDTf    = BC + (size_t)ROWS * 128;              // 48*1024*2
  float2* aDT     = (float2*)aDTf;
  float*  Tbuf    = aDTf + (size_t)2 * BATCH * NHEADS * SEQ;        // 768*4096
  float*  Ebuf    = Tbuf + (size_t)BATCH * NHEADS * NCH * 4096;     // 1024
  float*  Sinbuf  = Ebuf + 1024;                          // 768*4096
  float*  Woutbff = Sinbuf + (size_t)BATCH * NHEADS * NCH * 4096;   // 294912 floats

  // bf16 buffers aliased onto dead f32 regions (lifetimes verified):
  unsigned short* ubf    = (unsigned short*)Sinbuf;  // dead before interchunk writes
  unsigned short* Winbf  = (unsigned short*)Tbuf;    // dead before chunk_state writes
  unsigned short* Ybf    = (unsigned short*)Tbuf;    // Tbuf dead after interchunk
  unsigned short* Woutbf = (unsigned short*)Woutbff; // standalone

  // casts (one fused launch)
  cast_all_kernel<<<ROWS + NPAD_WIN + D_MODEL, 256, 0, stream>>>(
      u, Win, Wout, ubf, Winbf, Woutbf);

  // 1) proj = u @ Win.T   (MFMA bf16, dbuf 2-phase, 64x128 tiles)
  dim3 g1(NPAD_WIN / 128, ROWS / 64);    // (26,32) = 832 blocks
  gemm_bt_bf16<64, 128><<<g1, 256, 0, stream>>>(ubf, Winbf, proj, ROWS, D_PROJ, D_MODEL);

  // 2) LN(B), LN(C), a/DT
  prep_kernel<<<ROWS, 64, 0, stream>>>(proj, dt_bias, Bg, Bb, Cg, Cb, BC, aDT);

  // 3) chunked scan
  chunk_state_kernel<<<BATCH * NHEADS * NCH, 256, 0, stream>>>(proj, BC, aDT, Tbuf, Ebuf);
  interchunk_kernel<<<BATCH * NHEADS * 4, 256, 0, stream>>>(Tbuf, Ebuf, Sinbuf);
  chunk_output_kernel<<<BATCH * NHEADS * NCH, 256, 0, stream>>>(proj, BC, aDT, Sinbuf, Dv, Ybf);

  // 4) out = Ybuf @ Wout.T   (MFMA bf16, dbuf 2-phase, 64x64 tiles)
  dim3 g2(D_MODEL / 64, ROWS / 64);      // (12,32) = 384 blocks
  gemm_bt_bf16<64, 64><<<g2, 256, 0, stream>>>(Ybf, Woutbf, out, ROWS, D_MODEL, D_INNER);
}

// Round 5
// 125.825 us; speedup vs baseline: 9.9249x; 1.0168x over previous
//
#include <hip/hip_runtime.h>
#include <cstdint>

#define D_MODEL   768
#define D_STATE   64
#define D_INNER   1536
#define NHEADS    24
#define HEADDIM   64
#define D_PROJ    3248
#define BATCH     2
#define SEQ       1024
#define ROWS      (BATCH*SEQ)   // 2048
#define LN_EPS    1e-5f
#define A_FLOOR   1e-4f
#define QC        64            // chunk length
#define NCH       (SEQ/QC)      // 16
#define LDT       68            // padded LDS stride (floats)
#define NPAD_WIN  3328          // 3248 padded to multiple of 128

typedef __attribute__((ext_vector_type(8))) short short8;
typedef __attribute__((ext_vector_type(4))) float f32x4;

// round-to-nearest-even f32 -> bf16 bits
__device__ __forceinline__ unsigned short f2bf(float f) {
  union { float f; uint32_t u; } v; v.f = f;
  uint32_t r = (v.u + 0x7FFFu + ((v.u >> 16) & 1u)) >> 16;
  return (unsigned short)r;
}

__device__ __forceinline__ void gload_lds16(const void* g, void* l) {
  __builtin_amdgcn_global_load_lds(
      (const __attribute__((address_space(1))) unsigned int*)g,
      (__attribute__((address_space(3))) unsigned int*)l, 16, 0, 0);
}

// counted vmcnt wait (T4) — literal strings, compile-time dispatched
template <int N>
__device__ __forceinline__ void wait_vm() {
  static_assert(N == 0 || N == 2 || N == 3, "unsupported vmcnt");
  if constexpr (N == 0) asm volatile("s_waitcnt vmcnt(0)" ::: "memory");
  else if constexpr (N == 2) asm volatile("s_waitcnt vmcnt(2)" ::: "memory");
  else if constexpr (N == 3) asm volatile("s_waitcnt vmcnt(3)" ::: "memory");
}

// ---------------------------------------------------------------------------
// Fused casts: u (2048x768), Win (3248->3328 x768 zero-padded), Wout (768x1536)
// ---------------------------------------------------------------------------
__global__ __launch_bounds__(256) void cast_all_kernel(
    const float* __restrict__ u, const float* __restrict__ Win,
    const float* __restrict__ Wout, unsigned short* __restrict__ ubf,
    unsigned short* __restrict__ Winbf, unsigned short* __restrict__ Woutbf) {
  int b = blockIdx.x;
  const float* src; unsigned short* dst; int cols, srcRows, row;
  if (b < ROWS)                 { row = b;                    src = u;    dst = ubf;    cols = D_MODEL; srcRows = ROWS;   }
  else if (b < ROWS + NPAD_WIN) { row = b - ROWS;             src = Win;  dst = Winbf;  cols = D_MODEL; srcRows = D_PROJ; }
  else                          { row = b - ROWS - NPAD_WIN;  src = Wout; dst = Woutbf; cols = D_INNER; srcRows = D_MODEL;}
  const bool live = row < srcRows;
  for (int c = threadIdx.x * 4; c < cols; c += 256 * 4) {
    float4 v = make_float4(0.f, 0.f, 0.f, 0.f);
    if (live) v = *(const float4*)(src + (size_t)row * cols + c);
    ushort4 o;
    o.x = f2bf(v.x); o.y = f2bf(v.y); o.z = f2bf(v.z); o.w = f2bf(v.w);
    *(ushort4*)(dst + (size_t)row * cols + c) = o;
  }
}

// ---------------------------------------------------------------------------
// MFMA bf16 GEMM (NT), dbuf with COUNTED vmcnt pipeline (T4):
//   prologue: stage(0->buf0), stage(1->buf1)
//   iter t:   vmcnt(LPW or 0) ; s_barrier ; ds_read+MFMA(buf t&1) ;
//             s_barrier ; stage(t+2 -> buf t&1)
// Loads for tile t+1 stay in flight across the compute of tile t.
// A (M,K) bf16 rm, B (N,K) bf16 rm, C (M,N) f32. 256 thr = 4 waves (2x2).
// LDS per operand: [4 k-chunks][rows][8 bf16]; 1KB linear segs for gload_lds.
// ---------------------------------------------------------------------------
template <int TBM, int TBN>
__global__ __launch_bounds__(256) void gemm_bt_bf16(
    const unsigned short* __restrict__ A, const unsigned short* __restrict__ B,
    float* __restrict__ C, int M, int N, int K) {
  constexpr int MF = TBM / 32;
  constexpr int NF = TBN / 32;
  constexpr int NSA = TBM / 16;
  constexpr int NSB = TBN / 16;
  constexpr int LPW = (NSA + NSB) / 4;   // gload_lds per wave per tile (exact)
  static_assert((NSA + NSB) % 4 == 0, "segments must split evenly over waves");
  __shared__ unsigned short Asm[2][TBM * 32];
  __shared__ unsigned short Bsm[2][TBN * 32];

  const int tid = threadIdx.x;
  const int wv = tid >> 6, lane = tid & 63;
  const int bm = blockIdx.y * TBM, bn = blockIdx.x * TBN;
  const int wm = (wv & 1) * (TBM / 2);
  const int wn = (wv >> 1) * (TBN / 2);
  const int g = lane >> 4, r = lane & 15;

  f32x4 acc[MF][NF];
#pragma unroll
  for (int i = 0; i < MF; ++i)
#pragma unroll
    for (int j = 0; j < NF; ++j) acc[i][j] = (f32x4){0.f, 0.f, 0.f, 0.f};

  auto stage = [&](int k0, int buf) {
    for (int s = wv; s < NSA + NSB; s += 4) {
      if (s < NSA) {
        int chunk = s / (TBM / 64);
        int row0 = (s % (TBM / 64)) * 64;
        gload_lds16(A + (size_t)(bm + row0 + lane) * K + k0 + chunk * 8,
                    (void*)(&Asm[buf][s * 512]));
      } else {
        int s2 = s - NSA;
        int chunk = s2 / (TBN / 64);
        int row0 = (s2 % (TBN / 64)) * 64;
        gload_lds16(B + (size_t)(bn + row0 + lane) * K + k0 + chunk * 8,
                    (void*)(&Bsm[buf][s2 * 512]));
      }
    }
  };

  const int kTiles = K >> 5;   // >= 2 for all our shapes
  stage(0, 0);
  stage(32, 1);

  for (int t = 0; t < kTiles; ++t) {
    const int cur = t & 1;
    if (t + 1 < kTiles) wait_vm<LPW>();   // tile t landed; t+1 still in flight
    else                wait_vm<0>();     // final tile: drain
    __builtin_amdgcn_s_barrier();         // all waves' tile-t segments visible

    short8 a[MF], b[NF];
#pragma unroll
    for (int mf = 0; mf < MF; ++mf)
      a[mf] = *(const short8*)&Asm[cur][g * TBM * 8 + (wm + mf * 16 + r) * 8];
#pragma unroll
    for (int nf = 0; nf < NF; ++nf)
      b[nf] = *(const short8*)&Bsm[cur][g * TBN * 8 + (wn + nf * 16 + r) * 8];
#pragma unroll
    for (int mf = 0; mf < MF; ++mf)
#pragma unroll
      for (int nf = 0; nf < NF; ++nf)
        acc[mf][nf] = __builtin_amdgcn_mfma_f32_16x16x32_bf16(a[mf], b[nf], acc[mf][nf], 0, 0, 0);

    __builtin_amdgcn_s_barrier();         // all waves done reading buf[cur]
    if (t + 2 < kTiles) stage((t + 2) << 5, cur);
  }

  // C write: D row = (lane>>4)*4 + q, col = lane&15 (m89-verified layout)
#pragma unroll
  for (int mf = 0; mf < MF; ++mf) {
#pragma unroll
    for (int nf = 0; nf < NF; ++nf) {
      int col = bn + wn + nf * 16 + r;
      if (col < N) {
#pragma unroll
        for (int q = 0; q < 4; ++q) {
          int row = bm + wm + mf * 16 + g * 4 + q;
          C[(size_t)row * N + col] = acc[mf][nf][q];
        }
      }
    }
  }
}

// ---------------------------------------------------------------------------
// Prep: LN(B), LN(C) -> BC; a = A*DT (log-decay), DT -> aDT
// ---------------------------------------------------------------------------
__device__ __forceinline__ float softplusf(float x) {
  return (x > 20.f) ? x : log1pf(expf(x));
}

__device__ __forceinline__ float wave_sum64(float v) {
#pragma unroll
  for (int o = 32; o > 0; o >>= 1) v += __shfl_xor(v, o);
  return v;
}

__global__ __launch_bounds__(64) void prep_kernel(
    const float* __restrict__ proj, const float* __restrict__ dt_bias,
    const float* __restrict__ Bg, const float* __restrict__ Bb,
    const float* __restrict__ Cg, const float* __restrict__ Cb,
    float* __restrict__ BC, float2* __restrict__ aDT) {
  const int r = blockIdx.x;
  const int lane = threadIdx.x;
  const float* p = proj + (size_t)r * D_PROJ;

  float bp = p[2 * D_INNER + lane];
  float cp = p[2 * D_INNER + D_STATE + lane];

  float mb = wave_sum64(bp) * (1.f / 64.f);
  float mc = wave_sum64(cp) * (1.f / 64.f);
  float db = bp - mb, dc = cp - mc;
  float vb = wave_sum64(db * db) * (1.f / 64.f);
  float vc = wave_sum64(dc * dc) * (1.f / 64.f);
  float bn = db * rsqrtf(vb + LN_EPS) * Bg[lane] + Bb[lane];
  float cn = dc * rsqrtf(vc + LN_EPS) * Cg[lane] + Cb[lane];
  BC[(size_t)r * 128 + lane]      = bn;
  BC[(size_t)r * 128 + 64 + lane] = cn;

  if (lane < NHEADS) {
    float ddt = p[2 * D_INNER + 2 * D_STATE + lane];
    float dA  = p[2 * D_INNER + 2 * D_STATE + NHEADS + lane];
    float DT = softplusf(ddt + dt_bias[lane]);
    float Aa = fminf(-softplusf(dA), -A_FLOOR);
    int b = r >> 10;
    int t = r & 1023;
    aDT[((size_t)(b * NHEADS + lane) << 10) + t] = make_float2(Aa * DT, DT);
  }
}

__device__ __forceinline__ float wave_prefix_incl(float v, int lane) {
#pragma unroll
  for (int o = 1; o < 64; o <<= 1) {
    float w = __shfl_up(v, o);
    if (lane >= o) v += w;
  }
  return v;
}

// ---------------------------------------------------------------------------
// chunk_state: T_c[n][p] = sum_s DT_s*exp(csum_end - csum_s) * B_s[n]*x_s[p]
// ---------------------------------------------------------------------------
__global__ __launch_bounds__(256) void chunk_state_kernel(
    const float* __restrict__ proj, const float* __restrict__ BC,
    const float2* __restrict__ aDT, float* __restrict__ Tbuf,
    float* __restrict__ Ebuf) {
  const int blk = blockIdx.x;
  const int c = blk & (NCH - 1), bh = blk >> 4;
  const int b = bh / NHEADS, hh = bh % NHEADS;
  const int tid = threadIdx.x;

  __shared__ float Bs[QC][LDT];
  __shared__ float Xs[QC][LDT];
  __shared__ float coeff[QC];
  __shared__ float etot[1];

  if (tid < 64) {
    float2 ad = aDT[((size_t)bh << 10) + c * QC + tid];
    float cs = wave_prefix_incl(ad.x, tid);
    float tot = __shfl(cs, 63);
    coeff[tid] = ad.y * __expf(tot - cs);
    if (tid == 63) etot[0] = __expf(tot);
  }
  __syncthreads();

  for (int i = tid; i < 1024; i += 256) {
    int s = i >> 4;
    int q = (i & 15) * 4;
    int r = b * SEQ + c * QC + s;
    *(float4*)&Bs[s][q] = *(const float4*)(BC + (size_t)r * 128 + q);
    float4 xv = *(const float4*)(proj + (size_t)r * D_PROJ + D_INNER + hh * 64 + q);
    float cf = coeff[s];
    xv.x *= cf; xv.y *= cf; xv.z *= cf; xv.w *= cf;
    *(float4*)&Xs[s][q] = xv;
  }
  __syncthreads();

  const int ni = (tid & 15) * 4, pi = (tid >> 4) * 4;
  float acc[4][4];
#pragma unroll
  for (int i = 0; i < 4; ++i)
#pragma unroll
    for (int j = 0; j < 4; ++j) acc[i][j] = 0.f;

  for (int s = 0; s < QC; ++s) {
    float bn[4], xp[4];
    *(float4*)bn = *(float4*)&Bs[s][ni];
    *(float4*)xp = *(float4*)&Xs[s][pi];
#pragma unroll
    for (int i = 0; i < 4; ++i)
#pragma unroll
      for (int j = 0; j < 4; ++j)
        acc[i][j] = fmaf(bn[i], xp[j], acc[i][j]);
  }

  float* T = Tbuf + (size_t)blk * 4096;
#pragma unroll
  for (int i = 0; i < 4; ++i)
    *(float4*)(T + (size_t)(ni + i) * 64 + pi) =
        make_float4(acc[i][0], acc[i][1], acc[i][2], acc[i][3]);
  if (tid == 0) Ebuf[blk] = etot[0];
}

// ---------------------------------------------------------------------------
// interchunk: S_in[c+1] = E_c * S_in[c] + T_c
// ---------------------------------------------------------------------------
__global__ __launch_bounds__(256) void interchunk_kernel(
    const float* __restrict__ Tbuf, const float* __restrict__ Ebuf,
    float* __restrict__ Sinbuf) {
  const int bh = blockIdx.x >> 2, part = blockIdx.x & 3;
  const int tid = threadIdx.x;
  const size_t eo = (size_t)part * 1024 + tid * 4;
  float4 s = make_float4(0.f, 0.f, 0.f, 0.f);
#pragma unroll
  for (int c = 0; c < NCH; ++c) {
    size_t off = ((size_t)(bh * NCH + c)) * 4096 + eo;
    *(float4*)(Sinbuf + off) = s;
    float E = Ebuf[bh * NCH + c];
    float4 t4 = *(const float4*)(Tbuf + off);
    s.x = fmaf(E, s.x, t4.x);
    s.y = fmaf(E, s.y, t4.y);
    s.z = fmaf(E, s.z, t4.z);
    s.w = fmaf(E, s.w, t4.w);
  }
}

// ---------------------------------------------------------------------------
// chunk_output: intra+inter chunk Y, + D*x, silu(z) gate -> bf16 Ybuf
// ---------------------------------------------------------------------------
__global__ __launch_bounds__(256) void chunk_output_kernel(
    const float* __restrict__ proj, const float* __restrict__ BC,
    const float2* __restrict__ aDT, const float* __restrict__ Sinbuf,
    const float* __restrict__ Dv, unsigned short* __restrict__ Ybf) {
  const int blk = blockIdx.x;
  const int c = blk & (NCH - 1), bh = blk >> 4;
  const int b = bh / NHEADS, hh = bh % NHEADS;
  const int tid = threadIdx.x;

  __shared__ float smem[3 * 64 * LDT];
  __shared__ float csum[QC];
  __shared__ float DTs[QC];
  float (*CcT)[LDT] = (float(*)[LDT])smem;
  float (*BcT)[LDT] = (float(*)[LDT])(smem + 64 * LDT);
  float (*Sin)[LDT] = (float(*)[LDT])(smem + 2 * 64 * LDT);
  float (*Wb)[LDT]  = CcT;
  float (*Xs)[LDT]  = BcT;

  if (tid < 64) {
    float2 ad = aDT[((size_t)bh << 10) + c * QC + tid];
    csum[tid] = wave_prefix_incl(ad.x, tid);
    DTs[tid] = ad.y;
  }

  const size_t sin_base = (size_t)blk * 4096;
  for (int i = tid; i < 1024; i += 256) {
    int tt = i >> 4;
    int q = (i & 15) * 4;
    int r = b * SEQ + c * QC + tt;
    float4 bv = *(const float4*)(BC + (size_t)r * 128 + q);
    float4 cv = *(const float4*)(BC + (size_t)r * 128 + 64 + q);
    BcT[q + 0][tt] = bv.x; BcT[q + 1][tt] = bv.y;
    BcT[q + 2][tt] = bv.z; BcT[q + 3][tt] = bv.w;
    CcT[q + 0][tt] = cv.x; CcT[q + 1][tt] = cv.y;
    CcT[q + 2][tt] = cv.z; CcT[q + 3][tt] = cv.w;
    *(float4*)&Sin[tt][q] = *(const float4*)(Sinbuf + sin_base + (size_t)tt * 64 + q);
  }
  __syncthreads();

  const int ti = (tid & 15) * 4, si = (tid >> 4) * 4;
  float acc1[4][4], acc2[4][4];
#pragma unroll
  for (int i = 0; i < 4; ++i)
#pragma unroll
    for (int j = 0; j < 4; ++j) { acc1[i][j] = 0.f; acc2[i][j] = 0.f; }

  for (int n = 0; n < 64; ++n) {
    float cv[4], bv[4], sv[4];
    *(float4*)cv = *(float4*)&CcT[n][ti];
    *(float4*)bv = *(float4*)&BcT[n][si];
    *(float4*)sv = *(float4*)&Sin[n][si];
#pragma unroll
    for (int i = 0; i < 4; ++i)
#pragma unroll
      for (int j = 0; j < 4; ++j) {
        acc1[i][j] = fmaf(cv[i], bv[j], acc1[i][j]);
        acc2[i][j] = fmaf(cv[i], sv[j], acc2[i][j]);
      }
  }
  __syncthreads();

#pragma unroll
  for (int j = 0; j < 4; ++j) {
    int s = si + j;
    float dts = DTs[s], cs = csum[s];
    float w4[4];
#pragma unroll
    for (int i = 0; i < 4; ++i) {
      int t = ti + i;
      w4[i] = (s <= t) ? acc1[i][j] * __expf(csum[t] - cs) * dts : 0.f;
    }
    *(float4*)&Wb[s][ti] = *(float4*)w4;
  }
#pragma unroll
  for (int i = 0; i < 4; ++i) {
    float d = __expf(csum[ti + i]);
#pragma unroll
    for (int j = 0; j < 4; ++j) acc2[i][j] *= d;
  }
  for (int i = tid; i < 1024; i += 256) {
    int s = i >> 4;
    int q = (i & 15) * 4;
    int r = b * SEQ + c * QC + s;
    *(float4*)&Xs[s][q] = *(const float4*)(proj + (size_t)r * D_PROJ + D_INNER + hh * 64 + q);
  }
  __syncthreads();

  for (int s = 0; s < 64; ++s) {
    float wv[4], xv[4];
    *(float4*)wv = *(float4*)&Wb[s][ti];
    *(float4*)xv = *(float4*)&Xs[s][si];
#pragma unroll
    for (int i = 0; i < 4; ++i)
#pragma unroll
      for (int j = 0; j < 4; ++j)
        acc2[i][j] = fmaf(wv[i], xv[j], acc2[i][j]);
  }

  const float Dh = Dv[hh];
#pragma unroll
  for (int i = 0; i < 4; ++i) {
    int t = ti + i;
    int r = b * SEQ + c * QC + t;
    float zv[4];
    *(float4*)zv = *(const float4*)(proj + (size_t)r * D_PROJ + hh * 64 + si);
    ushort4 o;
    unsigned short* op = (unsigned short*)&o;
#pragma unroll
    for (int j = 0; j < 4; ++j) {
      float x = Xs[t][si + j];
      float y = acc2[i][j] + Dh * x;
      float z = zv[j];
      op[j] = f2bf(y * (z / (1.f + __expf(-z))));
    }
    *(ushort4*)(Ybf + (size_t)r * D_INNER + hh * 64 + si) = o;
  }
}

// ---------------------------------------------------------------------------
// Launch
// ---------------------------------------------------------------------------
extern "C" void kernel_launch(void* const* d_in, const int* in_sizes, int n_in,
                              void* d_out, int out_size, void* d_ws, size_t ws_size,
                              hipStream_t stream) {
  const float* u       = (const float*)d_in[0];
  const float* Win     = (const float*)d_in[1];
  const float* Wout    = (const float*)d_in[2];
  const float* dt_bias = (const float*)d_in[3];
  const float* Dv      = (const float*)d_in[4];
  const float* Bg      = (const float*)d_in[5];
  const float* Bb      = (const float*)d_in[6];
  const float* Cg      = (const float*)d_in[7];
  const float* Cb      = (const float*)d_in[8];
  float* out = (float*)d_out;

  float* ws = (float*)d_ws;
  float*  proj    = ws;                                   // 2048*3248
  float*  BC      = proj + (size_t)ROWS * D_PROJ;         // 2048*128
  float*  aDTf    = BC + (size_t)ROWS * 128;              // 48*1024*2
  float2* aDT     = (float2*)aDTf;
  float*  Tbuf    = aDTf + (size_t)2 * BATCH * NHEADS * SEQ;        // 768*4096
  float*  Ebuf    = Tbuf + (size_t)BATCH * NHEADS * NCH * 4096;     // 1024
  float*  Sinbuf  = Ebuf + 1024;                          // 768*4096
  float*  Woutbff = Sinbuf + (size_t)BATCH * NHEADS * NCH * 4096;   // 294912 floats

  // bf16 buffers aliased onto dead f32 regions (lifetimes verified):
  unsigned short* ubf    = (unsigned short*)Sinbuf;  // dead before interchunk writes
  unsigned short* Winbf  = (unsigned short*)Tbuf;    // dead before chunk_state writes
  unsigned short* Ybf    = (unsigned short*)Tbuf;    // Tbuf dead after interchunk
  unsigned short* Woutbf = (unsigned short*)Woutbff; // standalone

  // casts (one fused launch)
  cast_all_kernel<<<ROWS + NPAD_WIN + D_MODEL, 256, 0, stream>>>(
      u, Win, Wout, ubf, Winbf, Woutbf);

  // 1) proj = u @ Win.T   (MFMA bf16, counted-vmcnt dbuf, 64x128 tiles)
  dim3 g1(NPAD_WIN / 128, ROWS / 64);    // (26,32) = 832 blocks
  gemm_bt_bf16<64, 128><<<g1, 256, 0, stream>>>(ubf, Winbf, proj, ROWS, D_PROJ, D_MODEL);

  // 2) LN(B), LN(C), a/DT
  prep_kernel<<<ROWS, 64, 0, stream>>>(proj, dt_bias, Bg, Bb, Cg, Cb, BC, aDT);

  // 3) chunked scan
  chunk_state_kernel<<<BATCH * NHEADS * NCH, 256, 0, stream>>>(proj, BC, aDT, Tbuf, Ebuf);
  interchunk_kernel<<<BATCH * NHEADS * 4, 256, 0, stream>>>(Tbuf, Ebuf, Sinbuf);
  chunk_output_kernel<<<BATCH * NHEADS * NCH, 256, 0, stream>>>(proj, BC, aDT, Sinbuf, Dv, Ybf);

  // 4) out = Ybuf @ Wout.T   (MFMA bf16, counted-vmcnt dbuf, 64x64 tiles)
  dim3 g2(D_MODEL / 64, ROWS / 64);      // (12,32) = 384 blocks
  gemm_bt_bf16<64, 64><<<g2, 256, 0, stream>>>(Ybf, Woutbf, out, ROWS, D_MODEL, D_INNER);
}